// Round 1
// baseline (226.762 us; speedup 1.0000x reference)
//
#include <hip/hip_runtime.h>
#include <math.h>

#define M 50
#define SQRT5 2.2360679774997896f

__constant__ float c_zscale[5] = {0.25f, 0.2f, 0.08f, 400.0f, 10.0f};
__constant__ float c_zshift[5] = {0.0f, 0.0f, 0.0f, 800.0f, 12.0f};

#if __has_builtin(__builtin_amdgcn_sqrtf)
__device__ __forceinline__ float fsqrt(float x) { return __builtin_amdgcn_sqrtf(x); }
#else
__device__ __forceinline__ float fsqrt(float x) { return sqrtf(x); }
#endif

// ---------------------------------------------------------------------------
// Setup kernel: one block. Computes
//   inv_ls, prior_var, Zs (scaled inducing pts), K_ZZ, A = (K_ZZ + 1e-4 I)^-1
// via Gauss-Jordan in LDS, and writes the per-point-kernel constants to ws:
//   ws[0      .. 2500)  A (50x50, row-major)
//   ws[2500   .. 2750)  Zb[m][j]   = -2 * sqrt5 * Zs[m][j]
//   ws[2750   .. 2800)  z2s[m]     = | sqrt5 * Zs[m] |^2
//   ws[2800   .. 2805)  ils[j]     = sqrt5 * inv_ls[j]
//   ws[2805]            prior_var
// ---------------------------------------------------------------------------
__global__ void gp_setup(const float* __restrict__ log_ls,
                         const float* __restrict__ log_var,
                         const float* __restrict__ zraw,
                         float* __restrict__ ws) {
    __shared__ float s_ils[5];
    __shared__ float s_pv;
    __shared__ float s_Zs[M * 5];
    __shared__ float s_aug[M][2 * M];
    __shared__ float s_f[M];

    const int t = threadIdx.x;

    if (t == 0) s_pv = expf(log_var[0]);
    if (t < 5)  s_ils[t] = 1.0f / (expf(log_ls[t]) + 1e-8f);
    __syncthreads();

    if (t < M * 5) {
        int j = t % 5;
        float z = tanhf(zraw[t]) * c_zscale[j] + c_zshift[j];
        s_Zs[t] = z * s_ils[j];
    }
    __syncthreads();

    const float pv = s_pv;

    // Build augmented [K + 1e-4 I | I]
    for (int idx = t; idx < M * M; idx += blockDim.x) {
        int i = idx / M, q = idx % M;
        float d2 = 0.0f;
        #pragma unroll
        for (int j = 0; j < 5; ++j) {
            float df = s_Zs[i * 5 + j] - s_Zs[q * 5 + j];
            d2 = fmaf(df, df, d2);
        }
        float dd = d2 + 1e-8f;
        float d  = fsqrt(dd);
        float s  = SQRT5 * d;
        float kv = pv * (1.0f + s + (5.0f / 3.0f) * (d * d)) * expf(-s);
        s_aug[i][q]     = kv + (i == q ? 1e-4f : 0.0f);
        s_aug[i][M + q] = (i == q) ? 1.0f : 0.0f;
    }
    __syncthreads();

    // Gauss-Jordan (no pivoting; matrix is SPD + ridge)
    for (int p = 0; p < M; ++p) {
        float rp = 1.0f / s_aug[p][p];            // read before any writes
        if (t < M) s_f[t] = (t == p) ? 0.0f : s_aug[t][p];
        __syncthreads();
        if (t < 2 * M) s_aug[p][t] *= rp;
        __syncthreads();
        for (int idx = t; idx < M * 2 * M; idx += blockDim.x) {
            int i = idx / (2 * M), j = idx % (2 * M);
            if (i != p) s_aug[i][j] = fmaf(-s_f[i], s_aug[p][j], s_aug[i][j]);
        }
        __syncthreads();
    }

    // Emit ws
    for (int idx = t; idx < M * M; idx += blockDim.x) {
        int i = idx / M, q = idx % M;
        ws[idx] = s_aug[i][M + q];
    }
    if (t < M * 5) {
        ws[2500 + t] = -2.0f * SQRT5 * s_Zs[t];
    }
    if (t < M) {
        float z2 = 0.0f;
        #pragma unroll
        for (int j = 0; j < 5; ++j) {
            float v = SQRT5 * s_Zs[t * 5 + j];
            z2 = fmaf(v, v, z2);
        }
        ws[2750 + t] = z2;
    }
    if (t < 5) ws[2800 + t] = SQRT5 * s_ils[t];
    if (t == 0) ws[2805] = pv;
}

// ---------------------------------------------------------------------------
// Main kernel: one thread per query point.
//   u    = |sqrt5*(Xs - Zs_m)|^2 (clamped) + 5e-8   (= 5*(d2+1e-8))
//   s    = sqrt(u);  k_m = pv*(1 + s + u/3)*exp(-s)
//   red  = k^T A k  (A wave-uniform -> scalar loads, SGPR-operand FMAs)
//   out  = sqrt(max(pv - red, 1e-6))
// ---------------------------------------------------------------------------
__global__ __launch_bounds__(256) void gp_var(const float* __restrict__ x,
                                              const float* __restrict__ ws,
                                              float* __restrict__ out, int B) {
    const int gid = blockIdx.x * 256 + threadIdx.x;
    if (gid >= B) return;

    const float* __restrict__ A   = ws;
    const float* __restrict__ Zb  = ws + 2500;
    const float* __restrict__ z2s = ws + 2750;
    const float* __restrict__ ils = ws + 2800;
    const float pv = ws[2805];

    float xs[5];
    #pragma unroll
    for (int j = 0; j < 5; ++j) xs[j] = x[gid * 5 + j] * ils[j];

    float x2 = 0.0f;
    #pragma unroll
    for (int j = 0; j < 5; ++j) x2 = fmaf(xs[j], xs[j], x2);

    float k[M];
    #pragma unroll
    for (int m = 0; m < M; ++m) {
        float u = x2 + z2s[m];
        #pragma unroll
        for (int j = 0; j < 5; ++j) u = fmaf(Zb[m * 5 + j], xs[j], u);
        u = fmaxf(u, 0.0f) + 5e-8f;
        float s = fsqrt(u);
        float e = exp2f(s * -1.4426950408889634f);   // exp(-s)
        k[m] = pv * ((1.0f + s) + u * (1.0f / 3.0f)) * e;
    }

    float red = 0.0f;
    #pragma unroll
    for (int m = 0; m < M; ++m) {
        float tacc = 0.0f;
        #pragma unroll
        for (int n = 0; n < M; ++n) tacc = fmaf(A[m * M + n], k[n], tacc);
        red = fmaf(k[m], tacc, red);
    }

    out[gid] = fsqrt(fmaxf(pv - red, 1e-6f));
}

extern "C" void kernel_launch(void* const* d_in, const int* in_sizes, int n_in,
                              void* d_out, int out_size, void* d_ws, size_t ws_size,
                              hipStream_t stream) {
    const float* x    = (const float*)d_in[0];
    const float* ll   = (const float*)d_in[1];
    const float* lv   = (const float*)d_in[2];
    const float* zraw = (const float*)d_in[3];
    float* out = (float*)d_out;
    float* ws  = (float*)d_ws;

    const int B = in_sizes[0] / 5;

    hipLaunchKernelGGL(gp_setup, dim3(1), dim3(256), 0, stream, ll, lv, zraw, ws);
    const int grid = (B + 255) / 256;
    hipLaunchKernelGGL(gp_var, dim3(grid), dim3(256), 0, stream, x, ws, out, B);
}

// Round 2
// 109.947 us; speedup vs baseline: 2.0625x; 2.0625x over previous
//
#include <hip/hip_runtime.h>
#include <math.h>

#define M 50
#define SQRT5 2.2360679774997896f

__constant__ float c_zscale[5] = {0.25f, 0.2f, 0.08f, 400.0f, 10.0f};
__constant__ float c_zshift[5] = {0.0f, 0.0f, 0.0f, 800.0f, 12.0f};

#if __has_builtin(__builtin_amdgcn_sqrtf)
__device__ __forceinline__ float fsqrt(float x) { return __builtin_amdgcn_sqrtf(x); }
#else
__device__ __forceinline__ float fsqrt(float x) { return sqrtf(x); }
#endif

// ---------------------------------------------------------------------------
// ws layout (floats):
//   [0    .. 1275)  Ap: packed upper-tri of (A + A^T) with diag = A_mm,
//                   off-diag = A_mn + A_nm  (so red = sum_m k_m * sum_{n>=m} Ap*k_n)
//   [1280 .. 1530)  Zb[m][j] = -2*sqrt5*Zs[m][j]
//   [1536 .. 1586)  z2s[m]   = |sqrt5*Zs[m]|^2
//   [1600 .. 1605)  ils[j]   = sqrt5 * inv_ls[j]
//   [1606]          prior_var
// ---------------------------------------------------------------------------

// Setup: one block, 1024 threads. Augmented [K+1e-4 I | I] (50x100 = 5000
// elements) lives in REGISTERS, 5 per thread (compile-time indices via
// unrolled kk loop). Per pivot: publish row p + column p to LDS, barrier,
// 5 register FMAs per thread, barrier.
__global__ __launch_bounds__(1024) void gp_setup(const float* __restrict__ log_ls,
                                                 const float* __restrict__ log_var,
                                                 const float* __restrict__ zraw,
                                                 float* __restrict__ ws) {
    __shared__ float s_ils[5];
    __shared__ float s_pv;
    __shared__ float s_Zs[M * 5];
    __shared__ float s_f[M];        // column p of aug (pre-update values)
    __shared__ float s_row[2 * M];  // row p of aug (pre-normalize values)
    __shared__ float s_A[M][M];     // final inverse, for packing

    const int t = threadIdx.x;

    if (t == 0) s_pv = expf(log_var[0]);
    if (t < 5)  s_ils[t] = 1.0f / (expf(log_ls[t]) + 1e-8f);
    __syncthreads();
    if (t < M * 5) {
        int j = t % 5;
        s_Zs[t] = (tanhf(zraw[t]) * c_zscale[j] + c_zshift[j]) * s_ils[j];
    }
    __syncthreads();
    const float pv = s_pv;

    // Build owned elements of augmented matrix in registers
    float r[5];
    int   erow[5], ecol[5];
    bool  ev[5];
    #pragma unroll
    for (int kk = 0; kk < 5; ++kk) {
        int e = t + kk * 1024;
        ev[kk] = (e < M * 2 * M);
        int ee = ev[kk] ? e : 0;
        int i = ee / (2 * M), j = ee % (2 * M);
        erow[kk] = i; ecol[kk] = j;
        float v = 0.0f;
        if (ev[kk]) {
            if (j < M) {
                float d2 = 0.0f;
                #pragma unroll
                for (int q = 0; q < 5; ++q) {
                    float df = s_Zs[i * 5 + q] - s_Zs[j * 5 + q];
                    d2 = fmaf(df, df, d2);
                }
                float d = fsqrt(d2 + 1e-8f);
                float s = SQRT5 * d;
                v = pv * (1.0f + s + (5.0f / 3.0f) * (d * d)) * expf(-s)
                    + ((i == j) ? 1e-4f : 0.0f);
            } else {
                v = ((j - M) == i) ? 1.0f : 0.0f;
            }
        }
        r[kk] = v;
    }

    // Gauss-Jordan, 50 pivots (SPD + ridge, no pivoting needed)
    for (int p = 0; p < M; ++p) {
        #pragma unroll
        for (int kk = 0; kk < 5; ++kk) {
            if (ev[kk] && ecol[kk] == p) s_f[erow[kk]]   = r[kk];
            if (ev[kk] && erow[kk] == p) s_row[ecol[kk]] = r[kk];
        }
        __syncthreads();
        const float rp = 1.0f / s_row[p];
        #pragma unroll
        for (int kk = 0; kk < 5; ++kk) {
            float rowv = s_row[ecol[kk]] * rp;                 // normalized a[p][j]
            float upd  = fmaf(-s_f[erow[kk]], rowv, r[kk]);    // a[i][j] -= a[i][p]*a'[p][j]
            r[kk] = (erow[kk] == p) ? rowv : upd;
        }
        __syncthreads();
    }

    // Gather inverse (right half) into LDS
    #pragma unroll
    for (int kk = 0; kk < 5; ++kk)
        if (ev[kk] && ecol[kk] >= M) s_A[erow[kk]][ecol[kk] - M] = r[kk];
    __syncthreads();

    // Pack symmetric upper-tri with folded symmetrization+doubling
    if (t < M) {
        int off = t * M - (t * (t - 1)) / 2;
        ws[off] = s_A[t][t];
        for (int n = t + 1; n < M; ++n)
            ws[off + n - t] = s_A[t][n] + s_A[n][t];
    }
    if (t < M * 5) ws[1280 + t] = -2.0f * SQRT5 * s_Zs[t];
    if (t < M) {
        float z2 = 0.0f;
        #pragma unroll
        for (int q = 0; q < 5; ++q) {
            float v = SQRT5 * s_Zs[t * 5 + q];
            z2 = fmaf(v, v, z2);
        }
        ws[1536 + t] = z2;
    }
    if (t < 5)  ws[1600 + t] = SQRT5 * s_ils[t];
    if (t == 0) ws[1606] = pv;
}

// ---------------------------------------------------------------------------
// Main kernel: one thread per query point.
// ---------------------------------------------------------------------------
__global__ __launch_bounds__(256) void gp_var(const float* __restrict__ x,
                                              const float* __restrict__ ws,
                                              float* __restrict__ out, int B) {
    __shared__ float sx[1280];
    const int t = threadIdx.x;
    const int gid = blockIdx.x * 256 + t;
    const long long base = (long long)blockIdx.x * 1280;

    // Coalesced float4 staging of this block's 256x5 inputs
    {
        const long long tot = (long long)B * 5;
        const float4* xv = (const float4*)(x + base);
        for (int i = t; i < 320; i += 256) {
            if (base + (long long)i * 4 + 3 < tot) {
                ((float4*)sx)[i] = xv[i];
            }
        }
    }
    __syncthreads();
    if (gid >= B) return;

    const float* __restrict__ Ap  = ws;
    const float* __restrict__ Zb  = ws + 1280;
    const float* __restrict__ z2s = ws + 1536;
    const float* __restrict__ ils = ws + 1600;
    const float pv = ws[1606];

    float xs[5];
    #pragma unroll
    for (int j = 0; j < 5; ++j) xs[j] = sx[t * 5 + j] * ils[j];

    float x2 = 0.0f;
    #pragma unroll
    for (int j = 0; j < 5; ++j) x2 = fmaf(xs[j], xs[j], x2);

    float k[M];
    #pragma unroll
    for (int m = 0; m < M; ++m) {
        float u = x2 + z2s[m];
        #pragma unroll
        for (int j = 0; j < 5; ++j) u = fmaf(Zb[m * 5 + j], xs[j], u);
        u = fmaxf(u, 0.0f) + 5e-8f;
        float s = fsqrt(u);
        float e = exp2f(s * -1.4426950408889634f);   // exp(-s)
        k[m] = pv * ((1.0f + s) + u * (1.0f / 3.0f)) * e;
    }

    // red = k^T A k via packed upper-tri of (A + A^T)
    float red = 0.0f;
    int idx = 0;
    #pragma unroll
    for (int m = 0; m < M; ++m) {
        float tacc = 0.0f;
        #pragma unroll
        for (int n = m; n < M; ++n) {
            tacc = fmaf(Ap[idx], k[n], tacc);
            ++idx;
        }
        red = fmaf(k[m], tacc, red);
    }

    out[gid] = fsqrt(fmaxf(pv - red, 1e-6f));
}

extern "C" void kernel_launch(void* const* d_in, const int* in_sizes, int n_in,
                              void* d_out, int out_size, void* d_ws, size_t ws_size,
                              hipStream_t stream) {
    const float* x    = (const float*)d_in[0];
    const float* ll   = (const float*)d_in[1];
    const float* lv   = (const float*)d_in[2];
    const float* zraw = (const float*)d_in[3];
    float* out = (float*)d_out;
    float* ws  = (float*)d_ws;

    const int B = in_sizes[0] / 5;

    hipLaunchKernelGGL(gp_setup, dim3(1), dim3(1024), 0, stream, ll, lv, zraw, ws);
    const int grid = (B + 255) / 256;
    hipLaunchKernelGGL(gp_var, dim3(grid), dim3(256), 0, stream, x, ws, out, B);
}

// Round 3
// 102.869 us; speedup vs baseline: 2.2044x; 1.0688x over previous
//
#include <hip/hip_runtime.h>
#include <math.h>

#define M 50
#define SQRT5 2.2360679774997896f

__constant__ float c_zscale[5] = {0.25f, 0.2f, 0.08f, 400.0f, 10.0f};
__constant__ float c_zshift[5] = {0.0f, 0.0f, 0.0f, 800.0f, 12.0f};

#if __has_builtin(__builtin_amdgcn_sqrtf)
__device__ __forceinline__ float fsqrt(float x) { return __builtin_amdgcn_sqrtf(x); }
#else
__device__ __forceinline__ float fsqrt(float x) { return sqrtf(x); }
#endif

#if __has_builtin(__builtin_amdgcn_exp2f)
__device__ __forceinline__ float fexp2(float x) { return __builtin_amdgcn_exp2f(x); }
#else
__device__ __forceinline__ float fexp2(float x) { return exp2f(x); }
#endif

// ---------------------------------------------------------------------------
// ws layout (floats):
//   [0    .. 1275)  Ap: packed upper-tri of pv^2*(A + A^T), diag = pv^2*A_mm
//                   (pv folded here so gp_var's k' = k/pv needs no pv mul)
//   [1280 .. 1530)  Zb[m][j] = -2*sqrt5*Zs[m][j]
//   [1536 .. 1586)  z2s[m]   = |sqrt5*Zs[m]|^2 + 5e-8   (epsilon folded)
//   [1600 .. 1605)  ils[j]   = sqrt5 * inv_ls[j]
//   [1606]          prior_var
// ---------------------------------------------------------------------------
__global__ __launch_bounds__(1024) void gp_setup(const float* __restrict__ log_ls,
                                                 const float* __restrict__ log_var,
                                                 const float* __restrict__ zraw,
                                                 float* __restrict__ ws) {
    __shared__ float s_ils[5];
    __shared__ float s_pv;
    __shared__ float s_Zs[M * 5];
    __shared__ float s_f[M];        // column p of aug (pre-update values)
    __shared__ float s_row[2 * M];  // row p of aug (pre-normalize values)
    __shared__ float s_A[M][M];     // final inverse

    const int t = threadIdx.x;

    if (t == 0) s_pv = expf(log_var[0]);
    if (t < 5)  s_ils[t] = 1.0f / (expf(log_ls[t]) + 1e-8f);
    __syncthreads();
    if (t < M * 5) {
        int j = t % 5;
        s_Zs[t] = (tanhf(zraw[t]) * c_zscale[j] + c_zshift[j]) * s_ils[j];
    }
    __syncthreads();
    const float pv = s_pv;

    // Owned elements of augmented [K+1e-4 I | I] live in registers (5/thread)
    float r[5];
    int   erow[5], ecol[5];
    bool  ev[5];
    #pragma unroll
    for (int kk = 0; kk < 5; ++kk) {
        int e = t + kk * 1024;
        ev[kk] = (e < M * 2 * M);
        int ee = ev[kk] ? e : 0;
        int i = ee / (2 * M), j = ee % (2 * M);
        erow[kk] = i; ecol[kk] = j;
        float v = 0.0f;
        if (ev[kk]) {
            if (j < M) {
                float d2 = 0.0f;
                #pragma unroll
                for (int q = 0; q < 5; ++q) {
                    float df = s_Zs[i * 5 + q] - s_Zs[j * 5 + q];
                    d2 = fmaf(df, df, d2);
                }
                float d = fsqrt(d2 + 1e-8f);
                float s = SQRT5 * d;
                v = pv * (1.0f + s + (5.0f / 3.0f) * (d * d)) * expf(-s)
                    + ((i == j) ? 1e-4f : 0.0f);
            } else {
                v = ((j - M) == i) ? 1.0f : 0.0f;
            }
        }
        r[kk] = v;
    }

    // Gauss-Jordan, 50 pivots (SPD + ridge, no pivoting needed)
    for (int p = 0; p < M; ++p) {
        #pragma unroll
        for (int kk = 0; kk < 5; ++kk) {
            if (ev[kk] && ecol[kk] == p) s_f[erow[kk]]   = r[kk];
            if (ev[kk] && erow[kk] == p) s_row[ecol[kk]] = r[kk];
        }
        __syncthreads();
        const float rp = 1.0f / s_row[p];
        #pragma unroll
        for (int kk = 0; kk < 5; ++kk) {
            float rowv = s_row[ecol[kk]] * rp;                 // normalized a[p][j]
            float upd  = fmaf(-s_f[erow[kk]], rowv, r[kk]);    // a[i][j] -= a[i][p]*a'[p][j]
            r[kk] = (erow[kk] == p) ? rowv : upd;
        }
        __syncthreads();
    }

    // Gather inverse (right half) into LDS
    #pragma unroll
    for (int kk = 0; kk < 5; ++kk)
        if (ev[kk] && ecol[kk] >= M) s_A[erow[kk]][ecol[kk] - M] = r[kk];
    __syncthreads();

    // Parallel pack: upper-tri of pv^2*(A + A^T), diag = pv^2*A_mm
    const float pv2 = pv * pv;
    for (int e = t; e < M * M; e += 1024) {
        int m = e / M, n = e % M;
        if (n >= m) {
            int off = m * M - (m * (m - 1)) / 2 + (n - m);
            float v = (m == n) ? s_A[m][m] : (s_A[m][n] + s_A[n][m]);
            ws[off] = pv2 * v;
        }
    }
    if (t < M * 5) ws[1280 + t] = -2.0f * SQRT5 * s_Zs[t];
    if (t < M) {
        float z2 = 0.0f;
        #pragma unroll
        for (int q = 0; q < 5; ++q) {
            float v = SQRT5 * s_Zs[t * 5 + q];
            z2 = fmaf(v, v, z2);
        }
        ws[1536 + t] = z2 + 5e-8f;
    }
    if (t < 5)  ws[1600 + t] = SQRT5 * s_ils[t];
    if (t == 0) ws[1606] = pv;
}

// ---------------------------------------------------------------------------
// Main kernel: one thread per query point.
//   u   = |sqrt5*(Xs - Zs_m)|^2 + 5e-8  (epsilon pre-folded into z2s)
//   s   = sqrt(u);  k'_m = (1 + s + u/3) * exp(-s)        [pv folded into Ap]
//   red = k'^T Ap k'   (packed upper-tri, wave-uniform scalar loads)
//   out = sqrt(max(pv - red, 1e-6))
// k values are pinned in VGPRs via empty asm to forbid rematerialization
// (round-2 pathology: compiler chose 32 VGPRs and recomputed the k chain).
// ---------------------------------------------------------------------------
__global__ __launch_bounds__(256, 1) void gp_var(const float* __restrict__ x,
                                                 const float* __restrict__ ws,
                                                 float* __restrict__ out, int B) {
    __shared__ float sx[1280];
    const int t = threadIdx.x;
    const int gid = blockIdx.x * 256 + t;
    const long long base = (long long)blockIdx.x * 1280;

    // Coalesced float4 staging of this block's 256x5 inputs
    {
        const long long tot = (long long)B * 5;
        const float4* xv = (const float4*)(x + base);
        for (int i = t; i < 320; i += 256) {
            if (base + (long long)i * 4 + 3 < tot) {
                ((float4*)sx)[i] = xv[i];
            }
        }
    }
    __syncthreads();
    if (gid >= B) return;

    const float* __restrict__ Ap  = ws;
    const float* __restrict__ Zb  = ws + 1280;
    const float* __restrict__ z2s = ws + 1536;
    const float* __restrict__ ils = ws + 1600;
    const float pv = ws[1606];

    float xs[5];
    #pragma unroll
    for (int j = 0; j < 5; ++j) xs[j] = sx[t * 5 + j] * ils[j];

    float x2 = 0.0f;
    #pragma unroll
    for (int j = 0; j < 5; ++j) x2 = fmaf(xs[j], xs[j], x2);

    float k[M];
    #pragma unroll
    for (int m = 0; m < M; ++m) {
        float u = x2 + z2s[m];
        #pragma unroll
        for (int j = 0; j < 5; ++j) u = fmaf(Zb[m * 5 + j], xs[j], u);
        u = fmaxf(u, 5e-8f);
        float s = fsqrt(u);
        float e = fexp2(s * -1.4426950408889634f);          // exp(-s)
        float kv = fmaf(u, (1.0f / 3.0f), 1.0f + s) * e;
        asm volatile("" : "+v"(kv));                        // pin: no remat
        k[m] = kv;
    }

    // red = k'^T Ap k' via packed upper-tri
    float red = 0.0f;
    int idx = 0;
    #pragma unroll
    for (int m = 0; m < M; ++m) {
        float tacc = 0.0f;
        #pragma unroll
        for (int n = m; n < M; ++n) {
            tacc = fmaf(Ap[idx], k[n], tacc);
            ++idx;
        }
        red = fmaf(k[m], tacc, red);
    }

    out[gid] = fsqrt(fmaxf(pv - red, 1e-6f));
}

extern "C" void kernel_launch(void* const* d_in, const int* in_sizes, int n_in,
                              void* d_out, int out_size, void* d_ws, size_t ws_size,
                              hipStream_t stream) {
    const float* x    = (const float*)d_in[0];
    const float* ll   = (const float*)d_in[1];
    const float* lv   = (const float*)d_in[2];
    const float* zraw = (const float*)d_in[3];
    float* out = (float*)d_out;
    float* ws  = (float*)d_ws;

    const int B = in_sizes[0] / 5;

    hipLaunchKernelGGL(gp_setup, dim3(1), dim3(1024), 0, stream, ll, lv, zraw, ws);
    const int grid = (B + 255) / 256;
    hipLaunchKernelGGL(gp_var, dim3(grid), dim3(256), 0, stream, x, ws, out, B);
}